// Round 16
// baseline (87.109 us; speedup 1.0000x reference)
//
#include <hip/hip_runtime.h>
#include <math.h>

// Problem constants
#define QDIM 512     // 2^9 state dim
#define DD   128     // K*C_IN = input dim of quadratic form
#define LIN  4096
#define LOUT 4089    // (4096 - 7 - 1)/1 + 1
#define NC   16      // C_IN
#define NB   16      // batch

typedef __attribute__((ext_vector_type(8))) short bf16x8;
typedef __attribute__((ext_vector_type(4))) float f32x4;

// Scratch in device globals (NOT d_ws) — R5 lesson. Every element rewritten
// each call before read. R8+R11 lesson: NO persistent-grid barriers.
// R14 lesson: epilogue writes bounds-checked, one element per row.
__device__ float  g_B[QDIM * DD];          // A, row-major [i][j]
__device__ unsigned short g_Qh[DD * DD];   // bf16 hi part of Q
__device__ unsigned short g_Ql[DD * DD];   // bf16 residual of Q

// ---- bf16 helpers (RNE) ----
__device__ __forceinline__ unsigned short f2bf(float f) {
  union { float f; unsigned u; } v; v.f = f;
  unsigned u = v.u + 0x7FFFu + ((v.u >> 16) & 1u);
  return (unsigned short)(u >> 16);
}
__device__ __forceinline__ float bf2f(unsigned short h) {
  union { unsigned u; float f; } v; v.u = ((unsigned)h) << 16;
  return v.f;
}

// ---------------------------------------------------------------------------
// colA v3: A[:,j] = E*R3*E*R2*E*R1*e_j. One column per block, 1024 threads
// (16 waves -> 4 waves/SIMD on the active CUs; R15's 512 thr = 2/SIMD was
// latency-starved at VALUBusy 14%). Wave-private reg vector (i = lane*8+e);
// shfl butterflies (no barriers, wave-redundant); matvec: wave w computes
// rows [w*32, w*32+32), coalesced float4 E reads, unroll 4, xor-reduce.
// Per-row math/reduce order identical to R15 -> bitwise-same A.
// ---------------------------------------------------------------------------
__global__ __launch_bounds__(1024) void colA_kernel(const float* __restrict__ E,
                                                    const float* __restrict__ theta) {
  __shared__ float vbuf[QDIM];
  int j = blockIdx.x;
  int tid = threadIdx.x;
  int lane = tid & 63;
  int wid = tid >> 6;                      // 0..15

  float myv[8];
  #pragma unroll
  for (int e = 0; e < 8; ++e) myv[e] = (lane * 8 + e == j) ? 1.0f : 0.0f;

  #pragma unroll 1
  for (int l = 0; l < 3; ++l) {
    // ---- forward RY butterflies (qubit q <-> bit 8-q), in registers ----
    #pragma unroll
    for (int q = 0; q < 9; ++q) {
      float half = theta[l * 9 + q] * 0.5f;
      float c = cosf(half), s = sinf(half);
      int bit = 8 - q;
      if (bit >= 3) {
        int m = 1 << (bit - 3);            // lane-crossing
        bool up = (lane & m) != 0;
        #pragma unroll
        for (int e = 0; e < 8; ++e) {
          float pv = __shfl_xor(myv[e], m);
          myv[e] = up ? fmaf(s, pv, c * myv[e]) : fmaf(-s, pv, c * myv[e]);
        }
      } else {
        int m = 1 << bit;                  // in-register pairs
        #pragma unroll
        for (int e = 0; e < 8; ++e) {
          if (!(e & m)) {
            float x0 = myv[e], x1 = myv[e | m];
            myv[e]     = fmaf(-s, x1, c * x0);
            myv[e | m] = fmaf(s, x0, c * x1);
          }
        }
      }
    }
    // ---- matvec u = E * v : wave computes rows [wid*32, wid*32+32) ----
    __syncthreads();                       // prior vbuf reads complete
    #pragma unroll 1
    for (int rr = 0; rr < 32; rr += 4) {
      float sum0, sum1, sum2, sum3;
      {
        int r0 = wid * 32 + rr;
        const float4* er0 = (const float4*)&E[(size_t)(r0 + 0) * QDIM];
        const float4* er1 = (const float4*)&E[(size_t)(r0 + 1) * QDIM];
        const float4* er2 = (const float4*)&E[(size_t)(r0 + 2) * QDIM];
        const float4* er3 = (const float4*)&E[(size_t)(r0 + 3) * QDIM];
        float4 a0 = er0[lane * 2], b0 = er0[lane * 2 + 1];
        float4 a1 = er1[lane * 2], b1 = er1[lane * 2 + 1];
        float4 a2 = er2[lane * 2], b2 = er2[lane * 2 + 1];
        float4 a3 = er3[lane * 2], b3 = er3[lane * 2 + 1];
        sum0 = a0.x * myv[0]; sum1 = a1.x * myv[0];
        sum2 = a2.x * myv[0]; sum3 = a3.x * myv[0];
        sum0 = fmaf(a0.y, myv[1], sum0); sum1 = fmaf(a1.y, myv[1], sum1);
        sum2 = fmaf(a2.y, myv[1], sum2); sum3 = fmaf(a3.y, myv[1], sum3);
        sum0 = fmaf(a0.z, myv[2], sum0); sum1 = fmaf(a1.z, myv[2], sum1);
        sum2 = fmaf(a2.z, myv[2], sum2); sum3 = fmaf(a3.z, myv[2], sum3);
        sum0 = fmaf(a0.w, myv[3], sum0); sum1 = fmaf(a1.w, myv[3], sum1);
        sum2 = fmaf(a2.w, myv[3], sum2); sum3 = fmaf(a3.w, myv[3], sum3);
        sum0 = fmaf(b0.x, myv[4], sum0); sum1 = fmaf(b1.x, myv[4], sum1);
        sum2 = fmaf(b2.x, myv[4], sum2); sum3 = fmaf(b3.x, myv[4], sum3);
        sum0 = fmaf(b0.y, myv[5], sum0); sum1 = fmaf(b1.y, myv[5], sum1);
        sum2 = fmaf(b2.y, myv[5], sum2); sum3 = fmaf(b3.y, myv[5], sum3);
        sum0 = fmaf(b0.z, myv[6], sum0); sum1 = fmaf(b1.z, myv[6], sum1);
        sum2 = fmaf(b2.z, myv[6], sum2); sum3 = fmaf(b3.z, myv[6], sum3);
        sum0 = fmaf(b0.w, myv[7], sum0); sum1 = fmaf(b1.w, myv[7], sum1);
        sum2 = fmaf(b2.w, myv[7], sum2); sum3 = fmaf(b3.w, myv[7], sum3);
      }
      #pragma unroll
      for (int m = 1; m < 64; m <<= 1) {
        sum0 += __shfl_xor(sum0, m);
        sum1 += __shfl_xor(sum1, m);
        sum2 += __shfl_xor(sum2, m);
        sum3 += __shfl_xor(sum3, m);
      }
      if (lane == 0) {
        int bq = wid * 32 + rr;
        vbuf[bq + 0] = sum0; vbuf[bq + 1] = sum1;
        vbuf[bq + 2] = sum2; vbuf[bq + 3] = sum3;
      }
    }
    __syncthreads();
    #pragma unroll
    for (int e = 0; e < 8; ++e) myv[e] = vbuf[lane * 8 + e];
  }
  // vbuf holds A[:, j]; one element per row, bounds-checked (R14 lesson)
  if (tid < QDIM) g_B[(size_t)tid * DD + j] = vbuf[tid];
}

// ---------------------------------------------------------------------------
// formq (verbatim R9): Q[j1][j2] = sum_i sgn(i) A[i][j1] A[i][j2]; A = g_B.
// ---------------------------------------------------------------------------
__global__ __launch_bounds__(256) void formq_kernel() {
  const float* A = g_B;
  __shared__ float colA[QDIM];
  __shared__ float part[DD];
  int j1 = blockIdx.x;
  int tid = threadIdx.x;
  int j2 = tid & 127, h = tid >> 7;
  for (int i = tid; i < QDIM; i += 256) {
    float sgn = (i < 256) ? 1.0f : -1.0f;
    colA[i] = sgn * A[i * DD + j1];
  }
  __syncthreads();
  float a0 = 0.f, a1 = 0.f, a2 = 0.f, a3 = 0.f;
  int i0 = h * 256;
  #pragma unroll 8
  for (int i = i0; i < i0 + 256; i += 4) {
    a0 = fmaf(colA[i + 0], A[(i + 0) * DD + j2], a0);
    a1 = fmaf(colA[i + 1], A[(i + 1) * DD + j2], a1);
    a2 = fmaf(colA[i + 2], A[(i + 2) * DD + j2], a2);
    a3 = fmaf(colA[i + 3], A[(i + 3) * DD + j2], a3);
  }
  float sum = (a0 + a1) + (a2 + a3);
  if (h == 1) part[j2] = sum;
  __syncthreads();
  if (h == 0) {
    sum += part[j2];
    unsigned short hi = f2bf(sum);
    unsigned short lo = f2bf(sum - bf2f(hi));
    g_Qh[j1 * DD + j2] = hi;
    g_Ql[j1 * DD + j2] = lo;
  }
}

// ---------------------------------------------------------------------------
// quad (verbatim R9): MFMA split-bf16, 64-t tile, 4 waves x (16t x 128i).
// ---------------------------------------------------------------------------
__global__ __launch_bounds__(256, 4) void quad_mfma_kernel(const float* __restrict__ x,
                                                           float* __restrict__ out) {
  __shared__ float xs[NC][72];      // 71 used (64 t + 7 halo)
  int b = blockIdx.x;
  int t0 = blockIdx.y * 64;
  int tid = threadIdx.x;
  int lane = tid & 63;
  int w = tid >> 6;
  const float* xb = x + (size_t)b * NC * LIN;

  for (int idx = tid; idx < NC * 71; idx += 256) {
    int c = idx / 71, o = idx % 71;
    int g = t0 + o;
    xs[c][o] = (g < LIN) ? xb[c * LIN + g] : 0.0f;
  }
  __syncthreads();

  int lrow = lane & 15;
  int lgrp = lane >> 4;

  f32x4 acc[8];
  #pragma unroll
  for (int n = 0; n < 8; ++n) acc[n] = (f32x4){0.f, 0.f, 0.f, 0.f};

  #pragma unroll
  for (int kb = 0; kb < 4; ++kb) {
    int c = kb * 4 + lgrp;
    int tl = w * 16 + lrow;
    bf16x8 a_hi, a_lo;
    #pragma unroll
    for (int e = 0; e < 8; ++e) {
      float v = xs[c][tl + e];
      unsigned short hh = f2bf(v);
      unsigned short ll = f2bf(v - bf2f(hh));
      a_hi[e] = (short)hh;
      a_lo[e] = (short)ll;
    }
    #pragma unroll
    for (int n = 0; n < 8; ++n) {
      int off = (n * 16 + lrow) * DD + kb * 32 + lgrp * 8;
      bf16x8 b_hi = *(const bf16x8*)(g_Qh + off);
      bf16x8 b_lo = *(const bf16x8*)(g_Ql + off);
      acc[n] = __builtin_amdgcn_mfma_f32_16x16x32_bf16(a_hi, b_hi, acc[n], 0, 0, 0);
      acc[n] = __builtin_amdgcn_mfma_f32_16x16x32_bf16(a_hi, b_lo, acc[n], 0, 0, 0);
      acc[n] = __builtin_amdgcn_mfma_f32_16x16x32_bf16(a_lo, b_hi, acc[n], 0, 0, 0);
    }
  }

  float pd[4] = {0.f, 0.f, 0.f, 0.f};
  float pn[4] = {0.f, 0.f, 0.f, 0.f};
  #pragma unroll
  for (int n = 0; n < 8; ++n) {
    int i = n * 16 + lrow;
    int cc = i >> 3, ko = i & 7;
    #pragma unroll
    for (int r = 0; r < 4; ++r) {
      int tl = w * 16 + lgrp * 4 + r;
      float v = xs[cc][tl + ko];
      pd[r] = fmaf(acc[n][r], v, pd[r]);
      pn[r] = fmaf(v, v, pn[r]);
    }
  }
  #pragma unroll
  for (int r = 0; r < 4; ++r) {
    #pragma unroll
    for (int m = 1; m < 16; m <<= 1) {
      pd[r] += __shfl_xor(pd[r], m);
      pn[r] += __shfl_xor(pn[r], m);
    }
  }
  if (lrow == 0) {
    #pragma unroll
    for (int r = 0; r < 4; ++r) {
      int t = t0 + w * 16 + lgrp * 4 + r;
      if (t < LOUT) out[(size_t)b * LOUT + t] = pd[r] / (pn[r] + 1e-12f);
    }
  }
}

// ---------------------------------------------------------------------------

extern "C" void kernel_launch(void* const* d_in, const int* in_sizes, int n_in,
                              void* d_out, int out_size, void* d_ws, size_t ws_size,
                              hipStream_t stream) {
  const float* x     = (const float*)d_in[0];   // (16,16,4096) f32
  const float* E     = (const float*)d_in[1];   // (512,512)    f32
  const float* theta = (const float*)d_in[2];   // (3,9)        f32
  float* out = (float*)d_out;                   // (16,1,1,4089) f32
  (void)d_ws; (void)ws_size;

  colA_kernel<<<DD, 1024, 0, stream>>>(E, theta);  // -> g_B (A, 512x128)
  formq_kernel<<<DD, 256, 0, stream>>>();          // -> g_Qh/g_Ql
  quad_mfma_kernel<<<dim3(NB, 64), 256, 0, stream>>>(x, out);
}

// Round 17
// 80.703 us; speedup vs baseline: 1.0794x; 1.0794x over previous
//
#include <hip/hip_runtime.h>
#include <math.h>

// Problem constants
#define QDIM 512     // 2^9 state dim
#define DD   128     // K*C_IN = input dim of quadratic form
#define LIN  4096
#define LOUT 4089    // (4096 - 7 - 1)/1 + 1
#define NC   16      // C_IN
#define NB   16      // batch

typedef __attribute__((ext_vector_type(8))) short bf16x8;
typedef __attribute__((ext_vector_type(4))) float f32x4;

// Scratch in device globals (NOT d_ws) — R5 lesson. Every element rewritten
// each call before read. R8+R11: no grid barriers. R16 lesson: per-block
// E/W bytes are the wall (~60GB/s/CU L1 fill) -> keep blocks byte-light,
// minimize node count (edges ~13us each).
__device__ float  g_B[QDIM * DD];          // W1 f32
__device__ float  g_C[QDIM * DD];          // W2 f32
__device__ unsigned short g_Ah[QDIM * DD]; // A bf16 hi (row-major [i][j])
__device__ unsigned short g_Al[QDIM * DD]; // A bf16 residual

// ---- bf16 helpers (RNE) ----
__device__ __forceinline__ unsigned short f2bf(float f) {
  union { float f; unsigned u; } v; v.f = f;
  unsigned u = v.u + 0x7FFFu + ((v.u >> 16) & 1u);
  return (unsigned short)(u >> 16);
}
__device__ __forceinline__ float bf2f(unsigned short h) {
  union { unsigned u; float f; } v; v.u = ((unsigned)h) << 16;
  return v.f;
}

// ---------------------------------------------------------------------------
// Precompute (R9/R7 measured-good structure). Row i of E*R*W = (R^T e_i)^T W
// via transposed butterflies in REVERSE qubit order on the E-row in LDS.
// ---------------------------------------------------------------------------
__device__ __forceinline__ void butterfly_T(float* col, const float* theta,
                                            int l, int p) {
  #pragma unroll
  for (int qq = 0; qq < 9; ++qq) {
    int q = 8 - qq;                    // reverse order for transpose
    float half = theta[l * 9 + q] * 0.5f;
    float c = cosf(half), s = sinf(half);
    int right = QDIM >> (q + 1);
    int a = p >> (8 - q);
    int r = p & (right - 1);
    int i0 = (a * 2) * right + r;
    int i1 = i0 + right;
    float v0 = col[i0], v1 = col[i1];
    col[i0] = c * v0 + s * v1;         // transposed 2x2
    col[i1] = c * v1 - s * v0;
    __syncthreads();
  }
}

// W1[i][j] = (R1^T e_i)[j], j<128  -> g_B
__global__ __launch_bounds__(256) void w1_kernel(const float* __restrict__ E,
                                                 const float* __restrict__ theta) {
  __shared__ float erow[QDIM];
  int i = blockIdx.x;
  int p = threadIdx.x;
  erow[p]       = E[i * QDIM + p];
  erow[p + 256] = E[i * QDIM + p + 256];
  __syncthreads();
  butterfly_T(erow, theta, 0, p);
  if (p < DD) g_B[i * DD + p] = erow[p];
}

// W2[i][:] = (R2^T e_i)^T * W1   (g_B -> g_C)
__global__ __launch_bounds__(256) void mm1_kernel(const float* __restrict__ E,
                                                  const float* __restrict__ theta) {
  __shared__ float erow[QDIM];
  __shared__ float part[DD];
  int i = blockIdx.x;
  int tid = threadIdx.x;
  erow[tid]       = E[i * QDIM + tid];
  erow[tid + 256] = E[i * QDIM + tid + 256];
  __syncthreads();
  butterfly_T(erow, theta, 1, tid);

  int j = tid & 127, h = tid >> 7;
  float a0 = 0.f, a1 = 0.f, a2 = 0.f, a3 = 0.f;
  int m0 = h * 256;
  #pragma unroll 8
  for (int m = m0; m < m0 + 256; m += 4) {
    a0 = fmaf(erow[m + 0], g_B[(m + 0) * DD + j], a0);
    a1 = fmaf(erow[m + 1], g_B[(m + 1) * DD + j], a1);
    a2 = fmaf(erow[m + 2], g_B[(m + 2) * DD + j], a2);
    a3 = fmaf(erow[m + 3], g_B[(m + 3) * DD + j], a3);
  }
  float sum = (a0 + a1) + (a2 + a3);
  if (h == 1) part[j] = sum;
  __syncthreads();
  if (h == 0) g_C[i * DD + j] = sum + part[j];
}

// A[i][:] = (R3^T e_i)^T * W2   (g_C -> g_Ah/g_Al, bf16 split)
__global__ __launch_bounds__(256) void mm2_kernel(const float* __restrict__ E,
                                                  const float* __restrict__ theta) {
  __shared__ float erow[QDIM];
  __shared__ float part[DD];
  int i = blockIdx.x;
  int tid = threadIdx.x;
  erow[tid]       = E[i * QDIM + tid];
  erow[tid + 256] = E[i * QDIM + tid + 256];
  __syncthreads();
  butterfly_T(erow, theta, 2, tid);

  int j = tid & 127, h = tid >> 7;
  float a0 = 0.f, a1 = 0.f, a2 = 0.f, a3 = 0.f;
  int m0 = h * 256;
  #pragma unroll 8
  for (int m = m0; m < m0 + 256; m += 4) {
    a0 = fmaf(erow[m + 0], g_C[(m + 0) * DD + j], a0);
    a1 = fmaf(erow[m + 1], g_C[(m + 1) * DD + j], a1);
    a2 = fmaf(erow[m + 2], g_C[(m + 2) * DD + j], a2);
    a3 = fmaf(erow[m + 3], g_C[(m + 3) * DD + j], a3);
  }
  float sum = (a0 + a1) + (a2 + a3);
  if (h == 1) part[j] = sum;
  __syncthreads();
  if (h == 0) {
    sum += part[j];
    unsigned short hi = f2bf(sum);
    unsigned short lo = f2bf(sum - bf2f(hi));
    g_Ah[i * DD + j] = hi;
    g_Al[i * DD + j] = lo;
  }
}

// ---------------------------------------------------------------------------
// quadA: out[b,t] = sum_i sgn(i) P[t,i]^2 / (v^T v + eps), P = A v  (no Q!)
// 256-t tiles, 4 waves x 64 t-rows; MFMA split-bf16, K=128, N=512.
// A-frag: lane lrow = t-row within m-tile, lgrp = k-group (8 elems).
// B-frag: A[i = n*16+lrow][k contiguous]. C: col=lane&15 (=i), row=lgrp*4+r.
// ---------------------------------------------------------------------------
__global__ __launch_bounds__(256, 2) void quadA_kernel(const float* __restrict__ x,
                                                       float* __restrict__ out) {
  __shared__ float xs[NC][264];     // 263 used (256 t + 7 halo)
  int b = blockIdx.x;
  int t0 = blockIdx.y * 256;
  int tid = threadIdx.x;
  int lane = tid & 63;
  int w = tid >> 6;                 // wave: t-rows [w*64, w*64+64)
  const float* xb = x + (size_t)b * NC * LIN;

  #pragma unroll 1
  for (int c = 0; c < NC; ++c)
    for (int o = tid; o < 263; o += 256) {
      int g = t0 + o;
      xs[c][o] = (g < LIN) ? xb[c * LIN + g] : 0.0f;
    }
  __syncthreads();

  int lrow = lane & 15;
  int lgrp = lane >> 4;

  // Build resident a-frags (4 m-tiles x 4 k-blocks) + pn partials.
  bf16x8 a_hi[4][4], a_lo[4][4];
  float pn[4];
  #pragma unroll
  for (int m = 0; m < 4; ++m) {
    float s2 = 0.f;
    int tl = w * 64 + m * 16 + lrow;
    #pragma unroll
    for (int kb = 0; kb < 4; ++kb) {
      int c = kb * 4 + lgrp;
      #pragma unroll
      for (int e = 0; e < 8; ++e) {
        float v = xs[c][tl + e];
        unsigned short hh = f2bf(v);
        unsigned short ll = f2bf(v - bf2f(hh));
        a_hi[m][kb][e] = (short)hh;
        a_lo[m][kb][e] = (short)ll;
        s2 = fmaf(v, v, s2);
      }
    }
    s2 += __shfl_xor(s2, 16);       // sum the 4 k-groups -> full ||v||^2
    s2 += __shfl_xor(s2, 32);       // (lane holds pn for t-row lrow of tile m)
    pn[m] = s2;
  }

  float pd[4][4];
  #pragma unroll
  for (int m = 0; m < 4; ++m)
    #pragma unroll
    for (int r = 0; r < 4; ++r) pd[m][r] = 0.f;

  #pragma unroll 1
  for (int n = 0; n < 32; ++n) {    // i-tiles: i = n*16 + lrow
    f32x4 acc[4];
    #pragma unroll
    for (int m = 0; m < 4; ++m) acc[m] = (f32x4){0.f, 0.f, 0.f, 0.f};
    #pragma unroll
    for (int kb = 0; kb < 4; ++kb) {
      int off = (n * 16 + lrow) * DD + kb * 32 + lgrp * 8;
      bf16x8 b_hi = *(const bf16x8*)(g_Ah + off);
      bf16x8 b_lo = *(const bf16x8*)(g_Al + off);
      #pragma unroll
      for (int m = 0; m < 4; ++m) {
        acc[m] = __builtin_amdgcn_mfma_f32_16x16x32_bf16(a_hi[m][kb], b_hi, acc[m], 0, 0, 0);
        acc[m] = __builtin_amdgcn_mfma_f32_16x16x32_bf16(a_hi[m][kb], b_lo, acc[m], 0, 0, 0);
        acc[m] = __builtin_amdgcn_mfma_f32_16x16x32_bf16(a_lo[m][kb], b_hi, acc[m], 0, 0, 0);
      }
    }
    float sg = (n < 16) ? 1.0f : -1.0f;   // i<256 <=> n<16
    #pragma unroll
    for (int m = 0; m < 4; ++m)
      #pragma unroll
      for (int r = 0; r < 4; ++r)
        pd[m][r] = fmaf(sg * acc[m][r], acc[m][r], pd[m][r]);
  }

  // reduce pd over the 16 i-lanes; fetch pn for the C-frag's t-row
  #pragma unroll
  for (int m = 0; m < 4; ++m)
    #pragma unroll
    for (int r = 0; r < 4; ++r) {
      #pragma unroll
      for (int msk = 1; msk < 16; msk <<= 1)
        pd[m][r] += __shfl_xor(pd[m][r], msk);
    }
  float pnv[4][4];
  #pragma unroll
  for (int m = 0; m < 4; ++m)
    #pragma unroll
    for (int r = 0; r < 4; ++r)
      pnv[m][r] = __shfl(pn[m], lgrp * 4 + r);   // all lanes active

  if (lrow == 0) {
    #pragma unroll
    for (int m = 0; m < 4; ++m)
      #pragma unroll
      for (int r = 0; r < 4; ++r) {
        int t = t0 + w * 64 + m * 16 + lgrp * 4 + r;
        if (t < LOUT) out[(size_t)b * LOUT + t] = pd[m][r] / (pnv[m][r] + 1e-12f);
      }
  }
}

// ---------------------------------------------------------------------------

extern "C" void kernel_launch(void* const* d_in, const int* in_sizes, int n_in,
                              void* d_out, int out_size, void* d_ws, size_t ws_size,
                              hipStream_t stream) {
  const float* x     = (const float*)d_in[0];   // (16,16,4096) f32
  const float* E     = (const float*)d_in[1];   // (512,512)    f32
  const float* theta = (const float*)d_in[2];   // (3,9)        f32
  float* out = (float*)d_out;                   // (16,1,1,4089) f32
  (void)d_ws; (void)ws_size;

  w1_kernel<<<QDIM, 256, 0, stream>>>(E, theta);    // -> g_B (W1)
  mm1_kernel<<<QDIM, 256, 0, stream>>>(E, theta);   // g_B -> g_C (W2)
  mm2_kernel<<<QDIM, 256, 0, stream>>>(E, theta);   // g_C -> g_Ah/g_Al (A)
  quadA_kernel<<<dim3(NB, 16), 256, 0, stream>>>(x, out);
}

// Round 18
// 65.805 us; speedup vs baseline: 1.3237x; 1.2264x over previous
//
#include <hip/hip_runtime.h>
#include <math.h>

// Problem constants
#define QDIM 512     // 2^9 state dim
#define DD   128     // K*C_IN = input dim of quadratic form
#define LIN  4096
#define LOUT 4089    // (4096 - 7 - 1)/1 + 1
#define NC   16      // C_IN
#define NB   16      // batch

typedef __attribute__((ext_vector_type(8))) short bf16x8;
typedef __attribute__((ext_vector_type(4))) float f32x4;

// Scratch in device globals (NOT d_ws) — R5 lesson. Every element rewritten
// each call before read. R8+R11: no grid barriers. R16/R17 lessons:
// per-block private byte streams are the wall; keep 4 blocks/CU and stage
// shared operands in LDS. Node overhead ~10us each -> 4-node chain.
__device__ float  g_B[QDIM * DD];          // W1 f32
__device__ float  g_C[QDIM * DD];          // W2 f32
__device__ unsigned short g_Ah[QDIM * DD]; // A bf16 hi (row-major [i][j])
__device__ unsigned short g_Al[QDIM * DD]; // A bf16 residual

// ---- bf16 helpers (RNE) ----
__device__ __forceinline__ unsigned short f2bf(float f) {
  union { float f; unsigned u; } v; v.f = f;
  unsigned u = v.u + 0x7FFFu + ((v.u >> 16) & 1u);
  return (unsigned short)(u >> 16);
}
__device__ __forceinline__ float bf2f(unsigned short h) {
  union { unsigned u; float f; } v; v.u = ((unsigned)h) << 16;
  return v.f;
}

// ---------------------------------------------------------------------------
// Precompute (verbatim R17, measured-good). Row i of E*R*W = (R^T e_i)^T W.
// ---------------------------------------------------------------------------
__device__ __forceinline__ void butterfly_T(float* col, const float* theta,
                                            int l, int p) {
  #pragma unroll
  for (int qq = 0; qq < 9; ++qq) {
    int q = 8 - qq;                    // reverse order for transpose
    float half = theta[l * 9 + q] * 0.5f;
    float c = cosf(half), s = sinf(half);
    int right = QDIM >> (q + 1);
    int a = p >> (8 - q);
    int r = p & (right - 1);
    int i0 = (a * 2) * right + r;
    int i1 = i0 + right;
    float v0 = col[i0], v1 = col[i1];
    col[i0] = c * v0 + s * v1;         // transposed 2x2
    col[i1] = c * v1 - s * v0;
    __syncthreads();
  }
}

// W1[i][j] = (R1^T e_i)[j], j<128  -> g_B
__global__ __launch_bounds__(256) void w1_kernel(const float* __restrict__ E,
                                                 const float* __restrict__ theta) {
  __shared__ float erow[QDIM];
  int i = blockIdx.x;
  int p = threadIdx.x;
  erow[p]       = E[i * QDIM + p];
  erow[p + 256] = E[i * QDIM + p + 256];
  __syncthreads();
  butterfly_T(erow, theta, 0, p);
  if (p < DD) g_B[i * DD + p] = erow[p];
}

// W2[i][:] = (R2^T e_i)^T * W1   (g_B -> g_C)
__global__ __launch_bounds__(256) void mm1_kernel(const float* __restrict__ E,
                                                  const float* __restrict__ theta) {
  __shared__ float erow[QDIM];
  __shared__ float part[DD];
  int i = blockIdx.x;
  int tid = threadIdx.x;
  erow[tid]       = E[i * QDIM + tid];
  erow[tid + 256] = E[i * QDIM + tid + 256];
  __syncthreads();
  butterfly_T(erow, theta, 1, tid);

  int j = tid & 127, h = tid >> 7;
  float a0 = 0.f, a1 = 0.f, a2 = 0.f, a3 = 0.f;
  int m0 = h * 256;
  #pragma unroll 8
  for (int m = m0; m < m0 + 256; m += 4) {
    a0 = fmaf(erow[m + 0], g_B[(m + 0) * DD + j], a0);
    a1 = fmaf(erow[m + 1], g_B[(m + 1) * DD + j], a1);
    a2 = fmaf(erow[m + 2], g_B[(m + 2) * DD + j], a2);
    a3 = fmaf(erow[m + 3], g_B[(m + 3) * DD + j], a3);
  }
  float sum = (a0 + a1) + (a2 + a3);
  if (h == 1) part[j] = sum;
  __syncthreads();
  if (h == 0) g_C[i * DD + j] = sum + part[j];
}

// A[i][:] = (R3^T e_i)^T * W2   (g_C -> g_Ah/g_Al, bf16 split)
__global__ __launch_bounds__(256) void mm2_kernel(const float* __restrict__ E,
                                                  const float* __restrict__ theta) {
  __shared__ float erow[QDIM];
  __shared__ float part[DD];
  int i = blockIdx.x;
  int tid = threadIdx.x;
  erow[tid]       = E[i * QDIM + tid];
  erow[tid + 256] = E[i * QDIM + tid + 256];
  __syncthreads();
  butterfly_T(erow, theta, 2, tid);

  int j = tid & 127, h = tid >> 7;
  float a0 = 0.f, a1 = 0.f, a2 = 0.f, a3 = 0.f;
  int m0 = h * 256;
  #pragma unroll 8
  for (int m = m0; m < m0 + 256; m += 4) {
    a0 = fmaf(erow[m + 0], g_C[(m + 0) * DD + j], a0);
    a1 = fmaf(erow[m + 1], g_C[(m + 1) * DD + j], a1);
    a2 = fmaf(erow[m + 2], g_C[(m + 2) * DD + j], a2);
    a3 = fmaf(erow[m + 3], g_C[(m + 3) * DD + j], a3);
  }
  float sum = (a0 + a1) + (a2 + a3);
  if (h == 1) part[j] = sum;
  __syncthreads();
  if (h == 0) {
    sum += part[j];
    unsigned short hi = f2bf(sum);
    unsigned short lo = f2bf(sum - bf2f(hi));
    g_Ah[i * DD + j] = hi;
    g_Al[i * DD + j] = lo;
  }
}

// ---------------------------------------------------------------------------
// quadA v2: out[b,t] = sum_i sgn(i) (A v)_i^2 / (v^T v + eps).
// 1024 blocks (64-t tiles, 4/CU), 4 waves x 16 t-rows. A staged in LDS in
// 8 chunks of 64 i-rows (hi+lo = 32KB), XOR-swizzled (G4: row-major DD=128
// would be a 16-way bank conflict). Per-block L2 A-traffic = 256KB, read
// once cooperatively (vs R17's 256KB PER WAVE).
// Math order per t identical to R17 -> absmax canary 9.765625e-4.
// ---------------------------------------------------------------------------
__global__ __launch_bounds__(256, 4) void quadA_kernel(const float* __restrict__ x,
                                                       float* __restrict__ out) {
  __shared__ float xs[NC][72];                 // 71 used (64 t + 7 halo)
  __shared__ unsigned short sh_h[64 * DD];     // 16 KB, swizzled
  __shared__ unsigned short sh_l[64 * DD];     // 16 KB, swizzled
  int b = blockIdx.x;
  int t0 = blockIdx.y * 64;
  int tid = threadIdx.x;
  int lane = tid & 63;
  int w = tid >> 6;                            // wave: t-rows [w*16, w*16+16)
  const float* xb = x + (size_t)b * NC * LIN;

  for (int idx = tid; idx < NC * 71; idx += 256) {
    int c = idx / 71, o = idx % 71;
    int g = t0 + o;
    xs[c][o] = (g < LIN) ? xb[c * LIN + g] : 0.0f;
  }
  __syncthreads();

  int lrow = lane & 15;
  int lgrp = lane >> 4;

  // a-frags (4 k-blocks) + ||v||^2 partial (R17 math, m-dim collapsed to 1)
  bf16x8 a_hi[4], a_lo[4];
  float pn;
  {
    float s2 = 0.f;
    int tl = w * 16 + lrow;
    #pragma unroll
    for (int kb = 0; kb < 4; ++kb) {
      int c = kb * 4 + lgrp;
      #pragma unroll
      for (int e = 0; e < 8; ++e) {
        float v = xs[c][tl + e];
        unsigned short hh = f2bf(v);
        unsigned short ll = f2bf(v - bf2f(hh));
        a_hi[kb][e] = (short)hh;
        a_lo[kb][e] = (short)ll;
        s2 = fmaf(v, v, s2);
      }
    }
    s2 += __shfl_xor(s2, 16);
    s2 += __shfl_xor(s2, 32);
    pn = s2;
  }

  float pd[4] = {0.f, 0.f, 0.f, 0.f};

  #pragma unroll 1
  for (int ch = 0; ch < 8; ++ch) {
    __syncthreads();                           // prior chunk reads complete
    // stage 64 i-rows (hi+lo) with XOR swizzle: u16col ^= (row&7)<<3
    #pragma unroll
    for (int it = 0; it < 4; ++it) {
      int flat = it * 256 + tid;               // 1024 granules of 8 u16
      int row = flat >> 4;                     // 0..63
      int g8 = flat & 15;                      // granule within row
      int gidx = (ch * 64 + row) * DD + g8 * 8;
      int lidx = row * DD + ((g8 * 8) ^ ((row & 7) << 3));
      *(bf16x8*)&sh_h[lidx] = *(const bf16x8*)(g_Ah + gidx);
      *(bf16x8*)&sh_l[lidx] = *(const bf16x8*)(g_Al + gidx);
    }
    __syncthreads();

    #pragma unroll
    for (int nn = 0; nn < 4; ++nn) {           // i-tile: i = (ch*4+nn)*16 + lrow
      f32x4 acc = (f32x4){0.f, 0.f, 0.f, 0.f};
      int rowc = nn * 16 + lrow;
      int swz = (rowc & 7) << 3;
      #pragma unroll
      for (int kb = 0; kb < 4; ++kb) {
        int u16i = rowc * DD + ((kb * 32 + lgrp * 8) ^ swz);
        bf16x8 b_hi = *(const bf16x8*)&sh_h[u16i];
        bf16x8 b_lo = *(const bf16x8*)&sh_l[u16i];
        acc = __builtin_amdgcn_mfma_f32_16x16x32_bf16(a_hi[kb], b_hi, acc, 0, 0, 0);
        acc = __builtin_amdgcn_mfma_f32_16x16x32_bf16(a_hi[kb], b_lo, acc, 0, 0, 0);
        acc = __builtin_amdgcn_mfma_f32_16x16x32_bf16(a_lo[kb], b_hi, acc, 0, 0, 0);
      }
      float sg = (ch * 4 + nn < 16) ? 1.0f : -1.0f;   // i<256
      #pragma unroll
      for (int r = 0; r < 4; ++r)
        pd[r] = fmaf(sg * acc[r], acc[r], pd[r]);
    }
  }

  // reduce pd over the 16 i-lanes; fetch pn for the C-frag's t-row
  #pragma unroll
  for (int r = 0; r < 4; ++r) {
    #pragma unroll
    for (int msk = 1; msk < 16; msk <<= 1)
      pd[r] += __shfl_xor(pd[r], msk);
  }
  float pnv[4];
  #pragma unroll
  for (int r = 0; r < 4; ++r)
    pnv[r] = __shfl(pn, lgrp * 4 + r);         // all lanes active

  if (lrow == 0) {
    #pragma unroll
    for (int r = 0; r < 4; ++r) {
      int t = t0 + w * 16 + lgrp * 4 + r;
      if (t < LOUT) out[(size_t)b * LOUT + t] = pd[r] / (pnv[r] + 1e-12f);
    }
  }
}

// ---------------------------------------------------------------------------

extern "C" void kernel_launch(void* const* d_in, const int* in_sizes, int n_in,
                              void* d_out, int out_size, void* d_ws, size_t ws_size,
                              hipStream_t stream) {
  const float* x     = (const float*)d_in[0];   // (16,16,4096) f32
  const float* E     = (const float*)d_in[1];   // (512,512)    f32
  const float* theta = (const float*)d_in[2];   // (3,9)        f32
  float* out = (float*)d_out;                   // (16,1,1,4089) f32
  (void)d_ws; (void)ws_size;

  w1_kernel<<<QDIM, 256, 0, stream>>>(E, theta);    // -> g_B (W1)
  mm1_kernel<<<QDIM, 256, 0, stream>>>(E, theta);   // g_B -> g_C (W2)
  mm2_kernel<<<QDIM, 256, 0, stream>>>(E, theta);   // g_C -> g_Ah/g_Al (A)
  quadA_kernel<<<dim3(NB, 64), 256, 0, stream>>>(x, out);
}